// Round 6
// baseline (256.065 us; speedup 1.0000x reference)
//
#include <hip/hip_runtime.h>
#include <stdint.h>

#define QCNT 256
#define NKEYS 10000
#define DDIM 128
#define KSEL 10
#define OBSROW 28224  // 4*84*84
#define QG 8          // queries per block in part kernel (4 waves x 2)
#define CHUNK 512     // keys per block chunk
#define NCHUNK ((NKEYS + CHUNK - 1) / CHUNK)  // 20
#define TILE 64       // keys per LDS tile
#define LIST 8        // per-lane candidate list; lane sees <=8 keys per chunk
#define NCAND (NCHUNK * KSEL)  // 200 candidates per query

typedef float f4v __attribute__((ext_vector_type(4)));

// Monotone (dist, idx) -> u64 encoding; dist = k2 - 2*dot can be negative
// (q2 constant dropped); sign-flip trick keeps total order.
__device__ inline unsigned long long enc_key(float d, int n) {
  unsigned u = __float_as_uint(d);
  u ^= (unsigned)((int)u >> 31) | 0x80000000u;
  return ((unsigned long long)u << 32) | (unsigned)n;
}

__device__ inline void insert8(unsigned long long best[LIST],
                               unsigned long long key) {
  if (key < best[LIST - 1]) {
    best[LIST - 1] = key;
#pragma unroll
    for (int s = LIST - 1; s >= 1; --s) {
      if (best[s] < best[s - 1]) {
        unsigned long long t = best[s];
        best[s] = best[s - 1];
        best[s - 1] = t;
      }
    }
  }
}

__device__ inline unsigned long long wave_min_u64(unsigned long long w) {
#pragma unroll
  for (int off = 1; off < 64; off <<= 1) {
    unsigned long long o =
        (unsigned long long)__shfl_xor((long long)w, off, 64);
    if (o < w) w = o;
  }
  return w;
}

// ---------------------------------------------------------------------------
// Kernel 1: partial top-10 per (query-group, key-chunk). UNCHANGED since R3.
// R6: launched TWICE (idempotent, same outputs) purely to measure its
// duration as (dur_R6 - dur_R5). Remove the duplicate next round.
// ---------------------------------------------------------------------------
__global__ __launch_bounds__(256) void knn_part_kernel(
    const float* __restrict__ q, const float* __restrict__ k,
    unsigned long long* __restrict__ part) {
  const int qg   = blockIdx.x;  // 0..31
  const int ch   = blockIdx.y;  // 0..19
  const int tid  = threadIdx.x;
  const int lane = tid & 63;
  const int wv   = __builtin_amdgcn_readfirstlane(tid >> 6);  // uniform 0..3

  const int kbase = ch * CHUNK;
  const int kend  = (kbase + CHUNK < NKEYS) ? kbase + CHUNK : NKEYS;

  __shared__ float4 kl[TILE][DDIM / 4];  // 32 KB, swizzled columns

  const int qA = qg * QG + 2 * wv;
  const int qB = qA + 1;
  const float4* qArow = (const float4*)(q + (size_t)qA * DDIM);
  const float4* qBrow = (const float4*)(q + (size_t)qB * DDIM);

  unsigned long long bestA[LIST], bestB[LIST];
#pragma unroll
  for (int s = 0; s < LIST; ++s) {
    bestA[s] = ~0ULL;
    bestB[s] = ~0ULL;
  }

  const int ntiles = (kend - kbase + TILE - 1) / TILE;
  for (int t = 0; t < ntiles; ++t) {
    const int tb = kbase + t * TILE;
    __syncthreads();  // previous tile's readers done before overwrite
#pragma unroll
    for (int it = 0; it < (TILE * DDIM / 4) / 256; ++it) {
      int l   = tid + it * 256;
      int row = l >> 5;  // 0..63
      int c   = l & 31;
      int n   = tb + row;
      if (n < NKEYS) {
        kl[row][c ^ (row & 7)] = ((const float4*)(k + (size_t)n * DDIM))[c];
      }
    }
    __syncthreads();

    const int n = tb + lane;  // this lane's key
    if (n < kend) {
      float dA = 0.f, dB = 0.f, kk = 0.f;
#pragma unroll
      for (int j = 0; j < DDIM / 4; ++j) {
        float4 kv = kl[lane][j ^ (lane & 7)];
        float4 qa = qArow[j];  // uniform addr -> s_load
        float4 qb = qBrow[j];
        dA = fmaf(kv.x, qa.x, dA);
        dA = fmaf(kv.y, qa.y, dA);
        dA = fmaf(kv.z, qa.z, dA);
        dA = fmaf(kv.w, qa.w, dA);
        dB = fmaf(kv.x, qb.x, dB);
        dB = fmaf(kv.y, qb.y, dB);
        dB = fmaf(kv.z, qb.z, dB);
        dB = fmaf(kv.w, qb.w, dB);
        kk = fmaf(kv.x, kv.x, kk);
        kk = fmaf(kv.y, kv.y, kk);
        kk = fmaf(kv.z, kv.z, kk);
        kk = fmaf(kv.w, kv.w, kk);
      }
      insert8(bestA, enc_key(fmaf(-2.f, dA, kk), n));
      insert8(bestB, enc_key(fmaf(-2.f, dB, kk), n));
    }
  }

  unsigned long long* dstA = part + ((size_t)qA * NCHUNK + ch) * KSEL;
  unsigned long long* dstB = part + ((size_t)qB * NCHUNK + ch) * KSEL;

#pragma unroll 1
  for (int r = 0; r < KSEL; ++r) {
    unsigned long long w = wave_min_u64(bestA[0]);
    if (bestA[0] == w) {
#pragma unroll
      for (int s = 0; s < LIST - 1; ++s) bestA[s] = bestA[s + 1];
      bestA[LIST - 1] = ~0ULL;
    }
    if (lane == 0) dstA[r] = w;
  }
#pragma unroll 1
  for (int r = 0; r < KSEL; ++r) {
    unsigned long long w = wave_min_u64(bestB[0]);
    if (bestB[0] == w) {
#pragma unroll
      for (int s = 0; s < LIST - 1; ++s) bestB[s] = bestB[s + 1];
      bestB[LIST - 1] = ~0ULL;
    }
    if (lane == 0) dstB[r] = w;
  }
}

// ---------------------------------------------------------------------------
// Kernel 2: fused merge + gather. UNCHANGED from R5 (cached loads + NT
// stores, barrier-free redundant per-wave merge, scalar copy base).
// ---------------------------------------------------------------------------
__global__ __launch_bounds__(256) void knn_merge_gather_kernel(
    const float* __restrict__ obs, const unsigned long long* __restrict__ part,
    float* __restrict__ out) {
  const int b    = blockIdx.x;  // b = r*QCNT + q
  const int r    = b >> 8;      // QCNT == 256
  const int qq   = b & 255;
  const int tid  = threadIdx.x;
  const int lane = tid & 63;

  const unsigned long long* cp = part + (size_t)qq * NCAND;
  // NCAND=200: lane+128 <= 191 < 200 always valid; lane+192 valid for lane<8.
  unsigned long long c0 = cp[lane];
  unsigned long long c1 = cp[lane + 64];
  unsigned long long c2 = cp[lane + 128];
  unsigned long long c3 = (lane + 192 < NCAND) ? cp[lane + 192] : ~0ULL;
  unsigned long long w = ~0ULL;
#pragma unroll 1
  for (int round = 0; round <= r; ++round) {
    unsigned long long m = c0;
    m = (c1 < m) ? c1 : m;
    m = (c2 < m) ? c2 : m;
    m = (c3 < m) ? c3 : m;
    w = wave_min_u64(m);
    if (c0 == w) c0 = ~0ULL;
    if (c1 == w) c1 = ~0ULL;
    if (c2 == w) c2 = ~0ULL;
    if (c3 == w) c3 = ~0ULL;
  }
  // wave-uniform -> force into SGPR so the copy base is scalar
  const int src = __builtin_amdgcn_readfirstlane((int)(w & 0xffffffffu));

  const f4v* __restrict__ s = (const f4v*)(obs + (size_t)src * OBSROW);
  f4v* __restrict__ d       = (f4v*)(out + (size_t)b * OBSROW);
#pragma unroll 4
  for (int i = tid; i < OBSROW / 4; i += 256) {
    f4v v = s[i];  // cached load: L3 catches duplicate rows
    __builtin_nontemporal_store(v, &d[i]);
  }
}

extern "C" void kernel_launch(void* const* d_in, const int* in_sizes, int n_in,
                              void* d_out, int out_size, void* d_ws,
                              size_t ws_size, hipStream_t stream) {
  const float* q   = (const float*)d_in[0];  // [256,128]
  const float* k   = (const float*)d_in[1];  // [10000,128]
  const float* obs = (const float*)d_in[2];  // [10000,4,84,84]
  float* out = (float*)d_out;                // [10,256,4,84,84]

  unsigned long long* part = (unsigned long long*)d_ws;  // 409600 B

  // MEASUREMENT: part launched twice (idempotent). dur(R6)-dur(R5) = part's
  // duration. Output identical; remove duplicate after reading the split.
  knn_part_kernel<<<dim3(QCNT / QG, NCHUNK), 256, 0, stream>>>(q, k, part);
  knn_part_kernel<<<dim3(QCNT / QG, NCHUNK), 256, 0, stream>>>(q, k, part);
  knn_merge_gather_kernel<<<KSEL * QCNT, 256, 0, stream>>>(obs, part, out);
}

// Round 7
// 144.243 us; speedup vs baseline: 1.7752x; 1.7752x over previous
//
#include <hip/hip_runtime.h>
#include <stdint.h>

#define QCNT 256
#define NKEYS 10000
#define DDIM 128
#define KSEL 10
#define OBSROW 28224  // 4*84*84
#define QG 8          // queries per block in part kernel (4 waves x 2)
#define CHUNK 512     // keys per block chunk
#define NCHUNK ((NKEYS + CHUNK - 1) / CHUNK)  // 20
#define TILE 64       // keys per LDS tile
#define NTILE (CHUNK / TILE)  // 8 (lane owns 1 key per tile -> 8 keys)
#define NSEG 4        // 128 floats = 4 segments of 32 floats (8 float4)
#define SEGF4 8       // float4 per segment row
#define LIST 8        // per-lane candidate list; lane sees exactly 8 keys
#define NCAND (NCHUNK * KSEL)  // 200 candidates per query

typedef float f4v __attribute__((ext_vector_type(4)));

// Monotone (dist, idx) -> u64 encoding; dist = k2 - 2*dot can be negative
// (q2 constant dropped); sign-flip trick keeps total order.
__device__ inline unsigned long long enc_key(float d, int n) {
  unsigned u = __float_as_uint(d);
  u ^= (unsigned)((int)u >> 31) | 0x80000000u;
  return ((unsigned long long)u << 32) | (unsigned)n;
}

__device__ inline void insert8(unsigned long long best[LIST],
                               unsigned long long key) {
  if (key < best[LIST - 1]) {
    best[LIST - 1] = key;
#pragma unroll
    for (int s = LIST - 1; s >= 1; --s) {
      if (best[s] < best[s - 1]) {
        unsigned long long t = best[s];
        best[s] = best[s - 1];
        best[s - 1] = t;
      }
    }
  }
}

__device__ inline unsigned long long wave_min_u64(unsigned long long w) {
#pragma unroll
  for (int off = 1; off < 64; off <<= 1) {
    unsigned long long o =
        (unsigned long long)__shfl_xor((long long)w, off, 64);
    if (o < w) w = o;
  }
  return w;
}

// ---------------------------------------------------------------------------
// Kernel 1: partial top-10 per (query-group, key-chunk). R7 restructure:
// seg-outer / tile-inner. q segment lives in VGPRs (loaded once per seg,
// outside the hot loop) so the hot loop is pure ds_read_b128 + FMA -- no
// mixed s_load/ds_read lgkmcnt serialization per j-step. Per-key partial
// sums (8 keys/lane) persist in registers across segments. LDS tile is one
// 8 KB segment slice, row-padded +1 float4 (no XOR swizzle needed).
// ---------------------------------------------------------------------------
__global__ __launch_bounds__(256) void knn_part_kernel(
    const float* __restrict__ q, const float* __restrict__ k,
    unsigned long long* __restrict__ part) {
  const int qg   = blockIdx.x;  // 0..31
  const int ch   = blockIdx.y;  // 0..19
  const int tid  = threadIdx.x;
  const int lane = tid & 63;
  const int wv   = __builtin_amdgcn_readfirstlane(tid >> 6);  // uniform 0..3

  const int kbase = ch * CHUNK;
  const int kend  = (kbase + CHUNK < NKEYS) ? kbase + CHUNK : NKEYS;

  __shared__ f4v kl[TILE][SEGF4 + 1];  // 64 x 9 float4 = 9216 B, row-padded

  const int qA = qg * QG + 2 * wv;
  const int qB = qA + 1;
  const f4v* qArow = (const f4v*)(q + (size_t)qA * DDIM);
  const f4v* qBrow = (const f4v*)(q + (size_t)qB * DDIM);

  // Per-key accumulators: lane owns key (kbase + t*TILE + lane), t = 0..7.
  float dA[NTILE], dB[NTILE], kk[NTILE];
#pragma unroll
  for (int t = 0; t < NTILE; ++t) {
    dA[t] = 0.f;
    dB[t] = 0.f;
    kk[t] = 0.f;
  }

#pragma unroll 1
  for (int seg = 0; seg < NSEG; ++seg) {
    // q segment -> registers, once per seg (wave-uniform addr -> s_load ok,
    // and it's outside the hot loop either way).
    f4v qa[SEGF4], qb[SEGF4];
#pragma unroll
    for (int jj = 0; jj < SEGF4; ++jj) {
      qa[jj] = qArow[seg * SEGF4 + jj];
      qb[jj] = qBrow[seg * SEGF4 + jj];
    }

#pragma unroll 1
    for (int t = 0; t < NTILE; ++t) {
      const int tb = kbase + t * TILE;
      __syncthreads();  // previous slice's readers done before overwrite
      // Stage 64 keys x 32 floats (8 KB): 512 float4, 2 per thread.
      // m -> (row = m>>3, col = m&7): coalesced 128 B runs per row.
#pragma unroll
      for (int it = 0; it < 2; ++it) {
        int m   = tid + it * 256;
        int row = m >> 3;
        int col = m & 7;
        int n   = tb + row;
        if (n < NKEYS) {
          kl[row][col] =
              ((const f4v*)(k + (size_t)n * DDIM))[seg * SEGF4 + col];
        }
      }
      __syncthreads();

      if (tb + lane < kend) {
        float a = dA[t], b = dB[t], c = kk[t];
#pragma unroll
        for (int jj = 0; jj < SEGF4; ++jj) {
          f4v kv = kl[lane][jj];  // own row, pure DS dependency chain
          a = fmaf(kv.x, qa[jj].x, a);
          a = fmaf(kv.y, qa[jj].y, a);
          a = fmaf(kv.z, qa[jj].z, a);
          a = fmaf(kv.w, qa[jj].w, a);
          b = fmaf(kv.x, qb[jj].x, b);
          b = fmaf(kv.y, qb[jj].y, b);
          b = fmaf(kv.z, qb[jj].z, b);
          b = fmaf(kv.w, qb[jj].w, b);
          c = fmaf(kv.x, kv.x, c);
          c = fmaf(kv.y, kv.y, c);
          c = fmaf(kv.z, kv.z, c);
          c = fmaf(kv.w, kv.w, c);
        }
        dA[t] = a;
        dB[t] = b;
        kk[t] = c;
      }
    }
  }

  // Build per-lane sorted top-8 from the 8 owned keys, then extract.
  unsigned long long bestA[LIST], bestB[LIST];
#pragma unroll
  for (int s = 0; s < LIST; ++s) {
    bestA[s] = ~0ULL;
    bestB[s] = ~0ULL;
  }
#pragma unroll
  for (int t = 0; t < NTILE; ++t) {
    const int n = kbase + t * TILE + lane;
    if (n < kend) {
      insert8(bestA, enc_key(fmaf(-2.f, dA[t], kk[t]), n));
      insert8(bestB, enc_key(fmaf(-2.f, dB[t], kk[t]), n));
    }
  }

  unsigned long long* dstA = part + ((size_t)qA * NCHUNK + ch) * KSEL;
  unsigned long long* dstB = part + ((size_t)qB * NCHUNK + ch) * KSEL;

#pragma unroll 1
  for (int r = 0; r < KSEL; ++r) {
    unsigned long long w = wave_min_u64(bestA[0]);
    if (bestA[0] == w) {
#pragma unroll
      for (int s = 0; s < LIST - 1; ++s) bestA[s] = bestA[s + 1];
      bestA[LIST - 1] = ~0ULL;
    }
    if (lane == 0) dstA[r] = w;
  }
#pragma unroll 1
  for (int r = 0; r < KSEL; ++r) {
    unsigned long long w = wave_min_u64(bestB[0]);
    if (bestB[0] == w) {
#pragma unroll
      for (int s = 0; s < LIST - 1; ++s) bestB[s] = bestB[s + 1];
      bestB[LIST - 1] = ~0ULL;
    }
    if (lane == 0) dstB[r] = w;
  }
}

// ---------------------------------------------------------------------------
// Kernel 2: fused merge + gather. UNCHANGED from R5 (cached loads + NT
// stores, barrier-free redundant per-wave merge, scalar copy base).
// ---------------------------------------------------------------------------
__global__ __launch_bounds__(256) void knn_merge_gather_kernel(
    const float* __restrict__ obs, const unsigned long long* __restrict__ part,
    float* __restrict__ out) {
  const int b    = blockIdx.x;  // b = r*QCNT + q
  const int r    = b >> 8;      // QCNT == 256
  const int qq   = b & 255;
  const int tid  = threadIdx.x;
  const int lane = tid & 63;

  const unsigned long long* cp = part + (size_t)qq * NCAND;
  unsigned long long c0 = cp[lane];
  unsigned long long c1 = cp[lane + 64];
  unsigned long long c2 = cp[lane + 128];
  unsigned long long c3 = (lane + 192 < NCAND) ? cp[lane + 192] : ~0ULL;
  unsigned long long w = ~0ULL;
#pragma unroll 1
  for (int round = 0; round <= r; ++round) {
    unsigned long long m = c0;
    m = (c1 < m) ? c1 : m;
    m = (c2 < m) ? c2 : m;
    m = (c3 < m) ? c3 : m;
    w = wave_min_u64(m);
    if (c0 == w) c0 = ~0ULL;
    if (c1 == w) c1 = ~0ULL;
    if (c2 == w) c2 = ~0ULL;
    if (c3 == w) c3 = ~0ULL;
  }
  // wave-uniform -> force into SGPR so the copy base is scalar
  const int src = __builtin_amdgcn_readfirstlane((int)(w & 0xffffffffu));

  const f4v* __restrict__ s = (const f4v*)(obs + (size_t)src * OBSROW);
  f4v* __restrict__ d       = (f4v*)(out + (size_t)b * OBSROW);
#pragma unroll 4
  for (int i = tid; i < OBSROW / 4; i += 256) {
    f4v v = s[i];  // cached load: L3 catches duplicate rows
    __builtin_nontemporal_store(v, &d[i]);
  }
}

extern "C" void kernel_launch(void* const* d_in, const int* in_sizes, int n_in,
                              void* d_out, int out_size, void* d_ws,
                              size_t ws_size, hipStream_t stream) {
  const float* q   = (const float*)d_in[0];  // [256,128]
  const float* k   = (const float*)d_in[1];  // [10000,128]
  const float* obs = (const float*)d_in[2];  // [10000,4,84,84]
  float* out = (float*)d_out;                // [10,256,4,84,84]

  unsigned long long* part = (unsigned long long*)d_ws;  // 409600 B

  knn_part_kernel<<<dim3(QCNT / QG, NCHUNK), 256, 0, stream>>>(q, k, part);
  knn_merge_gather_kernel<<<KSEL * QCNT, 256, 0, stream>>>(obs, part, out);
}